// Round 1
// baseline (128.506 us; speedup 1.0000x reference)
//
#include <hip/hip_runtime.h>

// LayerNorm over last axis: input/gamma/beta all (B,S,D) fp32, D=1024.
// One wave (64 lanes) per row; 4 float4 loads per lane per tensor.
// Pure-register kernel: no LDS, wave-shuffle reduction only.

#define LN_D 1024
#define LN_EPS 5e-6f

__global__ __launch_bounds__(256) void LayerNorm_37855841747141_kernel(
    const float* __restrict__ x,
    const float* __restrict__ g,
    const float* __restrict__ b,
    float* __restrict__ out,
    int nrows) {
  const int gwave = (int)((blockIdx.x * blockDim.x + threadIdx.x) >> 6);  // one wave per row
  const int lane  = (int)(threadIdx.x & 63);
  if (gwave >= nrows) return;

  const size_t row_off = (size_t)gwave * LN_D;
  const float4* __restrict__ xr = (const float4*)(x + row_off);
  const float4* __restrict__ gr = (const float4*)(g + row_off);
  const float4* __restrict__ br = (const float4*)(b + row_off);
  float4* __restrict__ orow = (float4*)(out + row_off);

  // D/4 = 256 float4 per row; 64 lanes -> 4 float4 per lane. Coalesced:
  // lane i reads float4 index (lane + 64*chunk), consecutive 16B per lane.
  float4 xv[4], gv[4], bv[4];
#pragma unroll
  for (int i = 0; i < 4; ++i) {
    xv[i] = xr[lane + 64 * i];
    gv[i] = gr[lane + 64 * i];
    bv[i] = br[lane + 64 * i];
  }

  float s = 0.f, ss = 0.f;
#pragma unroll
  for (int i = 0; i < 4; ++i) {
    s  += xv[i].x + xv[i].y + xv[i].z + xv[i].w;
    ss += xv[i].x * xv[i].x + xv[i].y * xv[i].y +
          xv[i].z * xv[i].z + xv[i].w * xv[i].w;
  }

  // Wave-64 butterfly reduction (no LDS, no __syncthreads).
#pragma unroll
  for (int off = 32; off > 0; off >>= 1) {
    s  += __shfl_xor(s, off, 64);
    ss += __shfl_xor(ss, off, 64);
  }

  const float inv_d = 1.0f / (float)LN_D;
  const float mean = s * inv_d;
  const float var  = ss * inv_d - mean * mean;
  const float rstd = rsqrtf(var + LN_EPS);

#pragma unroll
  for (int i = 0; i < 4; ++i) {
    float4 o;
    o.x = (xv[i].x - mean) * rstd * gv[i].x + bv[i].x;
    o.y = (xv[i].y - mean) * rstd * gv[i].y + bv[i].y;
    o.z = (xv[i].z - mean) * rstd * gv[i].z + bv[i].z;
    o.w = (xv[i].w - mean) * rstd * gv[i].w + bv[i].w;
    orow[lane + 64 * i] = o;
  }
}

extern "C" void kernel_launch(void* const* d_in, const int* in_sizes, int n_in,
                              void* d_out, int out_size, void* d_ws, size_t ws_size,
                              hipStream_t stream) {
  const float* x = (const float*)d_in[0];
  const float* g = (const float*)d_in[1];
  const float* b = (const float*)d_in[2];
  float* out = (float*)d_out;

  const int nrows = in_sizes[0] / LN_D;  // 8192
  const int waves_per_block = 256 / 64;  // 4 rows per block
  const int grid = (nrows + waves_per_block - 1) / waves_per_block;

  LayerNorm_37855841747141_kernel<<<grid, 256, 0, stream>>>(x, g, b, out, nrows);
}

// Round 2
// 127.806 us; speedup vs baseline: 1.0055x; 1.0055x over previous
//
#include <hip/hip_runtime.h>

// LayerNorm over last axis: input/gamma/beta all (B,S,D) fp32, D=1024.
// One wave (64 lanes) per row; 4 float4 loads per lane per tensor.
//
// Occupancy-first structure (R1): hold only x (16 VGPR) + gamma (16 VGPR)
// across the reduction; stream beta per-chunk AFTER rstd is known. Live set
// ~50 VGPR -> __launch_bounds__(256,8) keeps us at <=64 VGPR = 8 waves/SIMD
// (32 waves/CU), 2x the MLP of the R0 version (which held x+g+b = 48 payload
// regs and fell off the vgpr=64 occupancy cliff).

#define LN_D 1024
#define LN_EPS 5e-6f

__global__ __launch_bounds__(256, 8) void LayerNorm_37855841747141_kernel(
    const float* __restrict__ x,
    const float* __restrict__ g,
    const float* __restrict__ b,
    float* __restrict__ out,
    int nrows) {
  const int gwave = (int)((blockIdx.x * blockDim.x + threadIdx.x) >> 6);  // one wave per row
  const int lane  = (int)(threadIdx.x & 63);
  if (gwave >= nrows) return;

  const size_t row_off = (size_t)gwave * LN_D;
  const float4* __restrict__ xr = (const float4*)(x + row_off);
  const float4* __restrict__ gr = (const float4*)(g + row_off);
  const float4* __restrict__ br = (const float4*)(b + row_off);
  float4* __restrict__ orow = (float4*)(out + row_off);

  // D/4 = 256 float4 per row; 64 lanes -> 4 float4 per lane, coalesced.
  // Issue x loads first (reduction depends only on x), then g loads whose
  // latency hides under the shuffle chain.
  float4 xv[4];
#pragma unroll
  for (int i = 0; i < 4; ++i) xv[i] = xr[lane + 64 * i];
  float4 gv[4];
#pragma unroll
  for (int i = 0; i < 4; ++i) gv[i] = gr[lane + 64 * i];

  float s = 0.f, ss = 0.f;
#pragma unroll
  for (int i = 0; i < 4; ++i) {
    s  += xv[i].x + xv[i].y + xv[i].z + xv[i].w;
    ss += xv[i].x * xv[i].x + xv[i].y * xv[i].y +
          xv[i].z * xv[i].z + xv[i].w * xv[i].w;
  }

  // Wave-64 butterfly reduction (no LDS, no __syncthreads).
#pragma unroll
  for (int off = 32; off > 0; off >>= 1) {
    s  += __shfl_xor(s, off, 64);
    ss += __shfl_xor(ss, off, 64);
  }

  const float inv_d = 1.0f / (float)LN_D;
  const float mean = s * inv_d;
  const float var  = ss * inv_d - mean * mean;
  const float rstd = rsqrtf(var + LN_EPS);

  // Stream beta transiently; x,g already resident.
#pragma unroll
  for (int i = 0; i < 4; ++i) {
    const float4 bv = br[lane + 64 * i];
    float4 o;
    o.x = (xv[i].x - mean) * rstd * gv[i].x + bv.x;
    o.y = (xv[i].y - mean) * rstd * gv[i].y + bv.y;
    o.z = (xv[i].z - mean) * rstd * gv[i].z + bv.z;
    o.w = (xv[i].w - mean) * rstd * gv[i].w + bv.w;
    orow[lane + 64 * i] = o;
  }
}

extern "C" void kernel_launch(void* const* d_in, const int* in_sizes, int n_in,
                              void* d_out, int out_size, void* d_ws, size_t ws_size,
                              hipStream_t stream) {
  const float* x = (const float*)d_in[0];
  const float* g = (const float*)d_in[1];
  const float* b = (const float*)d_in[2];
  float* out = (float*)d_out;

  const int nrows = in_sizes[0] / LN_D;  // 8192
  const int waves_per_block = 256 / 64;  // 4 rows per block
  const int grid = (nrows + waves_per_block - 1) / waves_per_block;

  LayerNorm_37855841747141_kernel<<<grid, 256, 0, stream>>>(x, g, b, out, nrows);
}